// Round 6
// baseline (96.781 us; speedup 1.0000x reference)
//
#include <hip/hip_runtime.h>
#include <stdint.h>
#include <math.h>

#define D_DIM 512
#define H_DIM 256
#define E_NUM 10
#define ROWS_PB 128
#define NSTEP 16

typedef float f16v __attribute__((ext_vector_type(16)));
typedef float f2 __attribute__((ext_vector_type(2)));

// ---------- precompute: packed weights pk[d][gate e0..9 | sim e0..9] + bias_g ----------
__global__ __launch_bounds__(256) void pre_wg(const float* __restrict__ Wp,
                                              const float* __restrict__ bp,
                                              const float* __restrict__ emb,
                                              float* __restrict__ pk,
                                              float* __restrict__ bg) {
  int gid = blockIdx.x * 256 + threadIdx.x;
  if (gid < E_NUM * D_DIM) {
    int d = gid / E_NUM;
    int e = gid - d * E_NUM;
    const float* wr = Wp + (size_t)d * H_DIM;
    const float* er = emb + (size_t)e * H_DIM;
    float s0 = 0.f, s1 = 0.f, s2 = 0.f, s3 = 0.f;
#pragma unroll 4
    for (int h = 0; h < H_DIM; h += 4) {
      float4 a = *(const float4*)(wr + h);
      float4 b = *(const float4*)(er + h);
      s0 = fmaf(a.x, b.x, s0); s1 = fmaf(a.y, b.y, s1);
      s2 = fmaf(a.z, b.z, s2); s3 = fmaf(a.w, b.w, s3);
    }
    pk[(size_t)d * 20 + e] = ((s0 + s1) + (s2 + s3)) * 0.0625f;
  } else if (gid < E_NUM * D_DIM + E_NUM) {
    int e = gid - E_NUM * D_DIM;
    const float* er = emb + (size_t)e * H_DIM;
    float s = 0.f;
    for (int h = 0; h < H_DIM; ++h) s = fmaf(bp[h], er[h], s);
    bg[e] = s * 0.0625f;
  }
}

// ---------- precompute: normalized expert rows into pk sim slots + trust*stale ----------
__global__ __launch_bounds__(64) void pre_en(const float* __restrict__ ef,
                                             const float* __restrict__ trust,
                                             const float* __restrict__ dtv,
                                             float* __restrict__ pk,
                                             float* __restrict__ cf) {
  int e = blockIdx.x, l = threadIdx.x;
  const float* row = ef + (size_t)e * D_DIM;
  float s = 0.f;
#pragma unroll
  for (int j = 0; j < D_DIM / 64; ++j) { float v = row[l + 64 * j]; s = fmaf(v, v, s); }
#pragma unroll
  for (int o = 32; o; o >>= 1) s += __shfl_xor(s, o, 64);
  float inv = 1.f / fmaxf(sqrtf(s), 1e-8f);
#pragma unroll
  for (int j = 0; j < D_DIM / 64; ++j) {
    int d = l + 64 * j;
    pk[(size_t)d * 20 + 10 + e] = row[d] * inv;
  }
  if (l == 0) cf[e] = trust[e] * expf(-0.001f * dtv[e]);
}

// element i (0..79) of the 5 SGPR x16 vectors; i compile-time under unroll
#define WVx(i) ((i) < 16 ? w0[(i) & 15] : (i) < 32 ? w1[(i) & 15] : \
                (i) < 48 ? w2[(i) & 15] : (i) < 64 ? w3[(i) & 15] : w4[(i) & 15])

// ---------- main: coalesced gload_lds staging + SGPR weights + pk-fma ----------
__global__ __launch_bounds__(256, 2) void router_main(
    const float* __restrict__ feat, const float* __restrict__ pk,
    const float* __restrict__ cf, const float* __restrict__ bg,
    float* __restrict__ out, int B) {
  __shared__ float lds[4][ROWS_PB * 32];                  // 4 x 16 KB
  const int t = threadIdx.x;
  const int l = t & 63;
  const int w = __builtin_amdgcn_readfirstlane(t >> 6);   // wave 0..3
  const int h = __builtin_amdgcn_readfirstlane(t >> 7);   // D-half 0..1
  const int p = t & 127;                                  // row within block
  const size_t r0 = (size_t)blockIdx.x * ROWS_PB;

  // staging: wave w call j stages rows w*8+32j+(l>>3); lane's source quad is
  // XOR-pre-swizzled so the LINEAR gload_lds dest realizes the swizzled layout.
  const int sr = w * 8 + (l >> 3);
  const int qg = (l & 7) ^ (l >> 3);
  const float* gbase = feat + (r0 + sr) * (size_t)D_DIM + ((qg >> 2) * 256 + (qg & 3) * 4);
  const int ldsbase = w * 8 * 32;

  f2 ag[5], as_[5], n2;
#pragma unroll
  for (int i = 0; i < 5; ++i) { ag[i] = f2{0.f, 0.f}; as_[i] = f2{0.f, 0.f}; }
  n2 = f2{0.f, 0.f};

  auto STAGE = [&](int buf, int c) {
#pragma unroll
    for (int j = 0; j < 4; ++j) {
      __builtin_amdgcn_global_load_lds(
          (const __attribute__((address_space(1))) uint32_t*)(gbase + (size_t)j * 32 * D_DIM + c * 16),
          (__attribute__((address_space(3))) uint32_t*)&lds[buf][ldsbase + j * 1024],
          16, 0, 0);
    }
  };

  auto COMPUTE = [&](int buf, int c) {
#pragma unroll
    for (int qq = 0; qq < 4; ++qq) {
      f16v w0, w1, w2, w3, w4;
      const float* wp = pk + (size_t)(h * 256 + c * 16 + qq * 4) * 20;  // wave-uniform
      asm volatile(
          "s_load_dwordx16 %0, %5, 0x0\n"
          "s_load_dwordx16 %1, %5, 0x40\n"
          "s_load_dwordx16 %2, %5, 0x80\n"
          "s_load_dwordx16 %3, %5, 0xc0\n"
          "s_load_dwordx16 %4, %5, 0x100\n"
          "s_waitcnt lgkmcnt(0)"
          : "=&s"(w0), "=&s"(w1), "=&s"(w2), "=&s"(w3), "=&s"(w4)
          : "s"(wp));
      const int slot = ((h << 2) + qq) ^ (p & 7);
      float4 f = *(const float4*)&lds[buf][p * 32 + slot * 4];
#pragma unroll
      for (int q = 0; q < 4; ++q) {
        const float fq = (q == 0) ? f.x : (q == 1) ? f.y : (q == 2) ? f.z : f.w;
        const f2 fq2 = {fq, fq};
#pragma unroll
        for (int j = 0; j < 5; ++j) {
          const int bgi = q * 20 + 2 * j;
          f2 wg2 = {WVx(bgi), WVx(bgi + 1)};
          ag[j] = __builtin_elementwise_fma(fq2, wg2, ag[j]);
        }
#pragma unroll
        for (int j = 0; j < 5; ++j) {
          const int bsi = q * 20 + 10 + 2 * j;
          f2 ws2 = {WVx(bsi), WVx(bsi + 1)};
          as_[j] = __builtin_elementwise_fma(fq2, ws2, as_[j]);
        }
      }
      f2 p0 = {f.x, f.y}, p1 = {f.z, f.w};
      n2 = __builtin_elementwise_fma(p0, p0, n2);
      n2 = __builtin_elementwise_fma(p1, p1, n2);
    }
  };

  // prologue: 3 buffers in flight (12 loads)
  STAGE(0, 0); STAGE(1, 1); STAGE(2, 2);

#pragma unroll 1
  for (int c = 0; c < NSTEP - 3; ++c) {
    asm volatile("s_waitcnt vmcnt(8) lgkmcnt(0)" ::: "memory");
    __builtin_amdgcn_s_barrier();
    __builtin_amdgcn_sched_barrier(0);
    STAGE((c + 3) & 3, c + 3);
    COMPUTE(c & 3, c);
  }
  asm volatile("s_waitcnt vmcnt(8) lgkmcnt(0)" ::: "memory");
  __builtin_amdgcn_s_barrier();
  __builtin_amdgcn_sched_barrier(0);
  COMPUTE(1, 13);
  asm volatile("s_waitcnt vmcnt(4) lgkmcnt(0)" ::: "memory");
  __builtin_amdgcn_s_barrier();
  __builtin_amdgcn_sched_barrier(0);
  COMPUTE(2, 14);
  asm volatile("s_waitcnt vmcnt(0) lgkmcnt(0)" ::: "memory");
  __builtin_amdgcn_s_barrier();
  __builtin_amdgcn_sched_barrier(0);
  COMPUTE(3, 15);

  float acc[21];
#pragma unroll
  for (int e = 0; e < E_NUM; ++e) { acc[e] = ag[e >> 1][e & 1]; acc[10 + e] = as_[e >> 1][e & 1]; }
  acc[20] = n2.x + n2.y;

  // ---------- cross-half reduction (reuse lds[0]; last buf read was lds[3]) ----------
  if (h) {
    float* rp = &lds[0][p * 23];
#pragma unroll
    for (int i = 0; i < 21; ++i) rp[i] = acc[i];
  }
  asm volatile("s_waitcnt lgkmcnt(0)" ::: "memory");
  __builtin_amdgcn_s_barrier();
  __builtin_amdgcn_sched_barrier(0);
  if (h == 0) {
    const float* rp = &lds[0][p * 23];
#pragma unroll
    for (int i = 0; i < 21; ++i) acc[i] += rp[i];

    const float inv = 1.f / fmaxf(sqrtf(acc[20]), 1e-8f);
    float probs[E_NUM];
    float m = -1e30f;
#pragma unroll
    for (int e = 0; e < E_NUM; ++e) {
      float logit = acc[e] + bg[e];
      float gate = 1.f / (1.f + __expf(-logit));
      float sim = fmaf(acc[10 + e] * inv, 0.5f, 0.5f);
      float sc = gate * cf[e] * sim;
      probs[e] = sc;
      m = fmaxf(m, sc);
    }
    float Z = 0.f;
#pragma unroll
    for (int e = 0; e < E_NUM; ++e) { float pe = __expf(probs[e] - m); probs[e] = pe; Z += pe; }
    const float invZ = 1.f / Z;
#pragma unroll
    for (int e = 0; e < E_NUM; ++e) probs[e] *= invZ;

    // stable top-3 (strict >, lowest index wins ties) == jax.lax.top_k
    int i0 = 0; float b0 = probs[0];
#pragma unroll
    for (int e = 1; e < E_NUM; ++e) if (probs[e] > b0) { b0 = probs[e]; i0 = e; }
    int i1 = -1; float b1 = -1.f;
#pragma unroll
    for (int e = 0; e < E_NUM; ++e) if (e != i0 && probs[e] > b1) { b1 = probs[e]; i1 = e; }
    int i2 = -1; float b2 = -1.f;
#pragma unroll
    for (int e = 0; e < E_NUM; ++e) if (e != i0 && e != i1 && probs[e] > b2) { b2 = probs[e]; i2 = e; }

    const float wnorm = 1.f / (b0 + b1 + b2);
    const size_t row = r0 + p;
    float* ow = out + row * 3;
    ow[0] = b0 * wnorm; ow[1] = b1 * wnorm; ow[2] = b2 * wnorm;
    float* oi = out + (size_t)B * 3 + row * 3;
    oi[0] = (float)i0; oi[1] = (float)i1; oi[2] = (float)i2;
    float* op = out + (size_t)B * 6 + row * E_NUM;
#pragma unroll
    for (int e = 0; e < E_NUM; ++e) op[e] = probs[e];
  }
}

extern "C" void kernel_launch(void* const* d_in, const int* in_sizes, int n_in,
                              void* d_out, int out_size, void* d_ws, size_t ws_size,
                              hipStream_t stream) {
  const float* feat  = (const float*)d_in[0];
  const float* Wp    = (const float*)d_in[1];
  const float* bp    = (const float*)d_in[2];
  const float* emb   = (const float*)d_in[3];
  const float* ef    = (const float*)d_in[4];
  const float* trust = (const float*)d_in[5];
  const float* dtv   = (const float*)d_in[6];
  float* out = (float*)d_out;

  float* pk = (float*)d_ws;                    // 512*20 = 10240 floats
  float* cf = pk + D_DIM * 20;                 // E_NUM
  float* bg = cf + E_NUM;                      // E_NUM

  const int B = in_sizes[0] / D_DIM;

  hipLaunchKernelGGL(pre_wg, dim3((E_NUM * D_DIM + E_NUM + 255) / 256), dim3(256),
                     0, stream, Wp, bp, emb, pk, bg);
  hipLaunchKernelGGL(pre_en, dim3(E_NUM), dim3(64), 0, stream, ef, trust, dtv, pk, cf);
  hipLaunchKernelGGL(router_main, dim3(B / ROWS_PB), dim3(256), 0, stream,
                     feat, pk, cf, bg, out, B);
}

// Round 8
// 81.600 us; speedup vs baseline: 1.1860x; 1.1860x over previous
//
#include <hip/hip_runtime.h>
#include <stdint.h>
#include <math.h>

#define D_DIM 512
#define H_DIM 256
#define E_NUM 10

typedef float f16v __attribute__((ext_vector_type(16)));
typedef float f2 __attribute__((ext_vector_type(2)));

// ---------- precompute: packed weights pk[d][gate e0..9 | sim e0..9] + bias_g ----------
__global__ __launch_bounds__(256) void pre_wg(const float* __restrict__ Wp,
                                              const float* __restrict__ bp,
                                              const float* __restrict__ emb,
                                              float* __restrict__ pk,
                                              float* __restrict__ bg) {
  int gid = blockIdx.x * 256 + threadIdx.x;
  if (gid < E_NUM * D_DIM) {
    int d = gid / E_NUM;
    int e = gid - d * E_NUM;
    const float* wr = Wp + (size_t)d * H_DIM;
    const float* er = emb + (size_t)e * H_DIM;
    float s0 = 0.f, s1 = 0.f, s2 = 0.f, s3 = 0.f;
#pragma unroll 4
    for (int h = 0; h < H_DIM; h += 4) {
      float4 a = *(const float4*)(wr + h);
      float4 b = *(const float4*)(er + h);
      s0 = fmaf(a.x, b.x, s0); s1 = fmaf(a.y, b.y, s1);
      s2 = fmaf(a.z, b.z, s2); s3 = fmaf(a.w, b.w, s3);
    }
    pk[(size_t)d * 20 + e] = ((s0 + s1) + (s2 + s3)) * 0.0625f;
  } else if (gid < E_NUM * D_DIM + E_NUM) {
    int e = gid - E_NUM * D_DIM;
    const float* er = emb + (size_t)e * H_DIM;
    float s = 0.f;
    for (int h = 0; h < H_DIM; ++h) s = fmaf(bp[h], er[h], s);
    bg[e] = s * 0.0625f;
  }
}

// ---------- precompute: normalized expert rows into pk sim slots + trust*stale ----------
__global__ __launch_bounds__(64) void pre_en(const float* __restrict__ ef,
                                             const float* __restrict__ trust,
                                             const float* __restrict__ dtv,
                                             float* __restrict__ pk,
                                             float* __restrict__ cf) {
  int e = blockIdx.x, l = threadIdx.x;
  const float* row = ef + (size_t)e * D_DIM;
  float s = 0.f;
#pragma unroll
  for (int j = 0; j < D_DIM / 64; ++j) { float v = row[l + 64 * j]; s = fmaf(v, v, s); }
#pragma unroll
  for (int o = 32; o; o >>= 1) s += __shfl_xor(s, o, 64);
  float inv = 1.f / fmaxf(sqrtf(s), 1e-8f);
#pragma unroll
  for (int j = 0; j < D_DIM / 64; ++j) {
    int d = l + 64 * j;
    pk[(size_t)d * 20 + 10 + e] = row[d] * inv;
  }
  if (l == 0) cf[e] = trust[e] * expf(-0.001f * dtv[e]);
}

// element i (0..79) of the 5 SGPR x16 vectors; i compile-time under unroll
#define WVx(i) ((i) < 16 ? w0[(i) & 15] : (i) < 32 ? w1[(i) & 15] : \
                (i) < 48 ? w2[(i) & 15] : (i) < 64 ? w3[(i) & 15] : w4[(i) & 15])

// ---------- main: wave-private coalesced staging + SGPR weights + pk-fma ----------
__global__ __launch_bounds__(256, 5) void router_main(
    const float* __restrict__ feat, const float* __restrict__ pk,
    const float* __restrict__ cf, const float* __restrict__ bg,
    float* __restrict__ out, int B) {
  __shared__ float lds[8192];                             // 4 waves x 2 bufs x 1024 f
  const int t = threadIdx.x;
  const int l = t & 63;
  const int w = __builtin_amdgcn_readfirstlane(t >> 6);   // wave = d-quarter 0..3
  const size_t r0 = (size_t)blockIdx.x * 64;
  const int wbase = w * 2048;

  // staging lane map: lane i -> row (i>>2), slot (i&3); source quad XOR-pre-swizzled
  const int rpp = l >> 2;
  const int qsw = (l & 3) ^ (rpp & 3) ^ ((rpp >> 2) & 3);
  const float* gsrc = feat + (r0 + rpp) * (size_t)D_DIM + w * 128 + qsw * 4;
  // consumer: lane l = row l; quad qq lives at slot qq ^ (l&3) ^ ((l>>2)&3)
  const int csw = ((l & 3) ^ ((l >> 2) & 3)) << 2;

  f2 ag[5], as_[5], n2;
#pragma unroll
  for (int i = 0; i < 5; ++i) { ag[i] = f2{0.f, 0.f}; as_[i] = f2{0.f, 0.f}; }
  n2 = f2{0.f, 0.f};

  auto STAGE = [&](int buf, int c) {
#pragma unroll
    for (int j = 0; j < 4; ++j) {
      __builtin_amdgcn_global_load_lds(
          (const __attribute__((address_space(1))) uint32_t*)(gsrc + (size_t)j * 16 * D_DIM + c * 16),
          (__attribute__((address_space(3))) uint32_t*)&lds[wbase + buf * 1024 + j * 256 + (l << 2)],
          16, 0, 0);
    }
  };

  auto COMPUTE = [&](int buf, int c) {
#pragma unroll
    for (int qq = 0; qq < 4; ++qq) {
      f16v w0, w1, w2, w3, w4;
      const float* wp = pk + (size_t)(w * 128 + c * 16 + qq * 4) * 20;  // wave-uniform
      asm volatile(
          "s_load_dwordx16 %0, %5, 0x0\n"
          "s_load_dwordx16 %1, %5, 0x40\n"
          "s_load_dwordx16 %2, %5, 0x80\n"
          "s_load_dwordx16 %3, %5, 0xc0\n"
          "s_load_dwordx16 %4, %5, 0x100\n"
          "s_waitcnt lgkmcnt(0)"
          : "=&s"(w0), "=&s"(w1), "=&s"(w2), "=&s"(w3), "=&s"(w4)
          : "s"(wp));
      float4 f = *(const float4*)&lds[wbase + buf * 1024 + l * 16 + ((qq << 2) ^ csw)];
#pragma unroll
      for (int q = 0; q < 4; ++q) {
        const float fq = (q == 0) ? f.x : (q == 1) ? f.y : (q == 2) ? f.z : f.w;
        const f2 fq2 = {fq, fq};
#pragma unroll
        for (int j = 0; j < 5; ++j) {
          const int bgi = q * 20 + 2 * j;
          f2 wg2 = {WVx(bgi), WVx(bgi + 1)};
          ag[j] = __builtin_elementwise_fma(fq2, wg2, ag[j]);
        }
#pragma unroll
        for (int j = 0; j < 5; ++j) {
          const int bsi = q * 20 + 10 + 2 * j;
          f2 ws2 = {WVx(bsi), WVx(bsi + 1)};
          as_[j] = __builtin_elementwise_fma(fq2, ws2, as_[j]);
        }
      }
      f2 p0 = {f.x, f.y}, p1 = {f.z, f.w};
      n2 = __builtin_elementwise_fma(p0, p0, n2);
      n2 = __builtin_elementwise_fma(p1, p1, n2);
    }
  };

  // wave-private pipeline: 8 chunks of 16 d; 2 chunks (8 loads) in flight.
  // RACE FIX (R7 tripwire): before re-staging into the buffer just consumed,
  // drain ds_reads (lgkmcnt(0)) and pin order with sched_barrier so the DMA
  // write cannot land before a queued ds_read executes on hot replays.
  STAGE(0, 0); STAGE(1, 1);
#pragma unroll 1
  for (int c = 0; c < 6; ++c) {
    asm volatile("s_waitcnt vmcnt(4)" ::: "memory");      // chunk c landed
    __builtin_amdgcn_sched_barrier(0);
    COMPUTE(c & 1, c);
    asm volatile("s_waitcnt lgkmcnt(0)" ::: "memory");    // ds_reads of buf done
    __builtin_amdgcn_sched_barrier(0);
    STAGE(c & 1, c + 2);                                  // safe to reuse buffer
  }
  asm volatile("s_waitcnt vmcnt(4)" ::: "memory");
  __builtin_amdgcn_sched_barrier(0);
  COMPUTE(0, 6);
  asm volatile("s_waitcnt vmcnt(0)" ::: "memory");
  __builtin_amdgcn_sched_barrier(0);
  COMPUTE(1, 7);

  float acc[21];
#pragma unroll
  for (int e = 0; e < E_NUM; ++e) { acc[e] = ag[e >> 1][e & 1]; acc[10 + e] = as_[e >> 1][e & 1]; }
  acc[20] = n2.x + n2.y;

  // ---------- cross-wave reduction: each wave writes into ITS OWN region ----------
  if (w) {
    float* rp = &lds[wbase + l * 24];
#pragma unroll
    for (int i = 0; i < 21; ++i) rp[i] = acc[i];
  }
  __syncthreads();
  if (w == 0) {
#pragma unroll
    for (int s = 1; s < 4; ++s) {
      const float* rp = &lds[s * 2048 + l * 24];
#pragma unroll
      for (int i = 0; i < 21; ++i) acc[i] += rp[i];
    }

    const float inv = 1.f / fmaxf(sqrtf(acc[20]), 1e-8f);
    float probs[E_NUM];
    float m = -1e30f;
#pragma unroll
    for (int e = 0; e < E_NUM; ++e) {
      float logit = acc[e] + bg[e];
      float gate = 1.f / (1.f + __expf(-logit));
      float sim = fmaf(acc[10 + e] * inv, 0.5f, 0.5f);
      float sc = gate * cf[e] * sim;
      probs[e] = sc;
      m = fmaxf(m, sc);
    }
    float Z = 0.f;
#pragma unroll
    for (int e = 0; e < E_NUM; ++e) { float pe = __expf(probs[e] - m); probs[e] = pe; Z += pe; }
    const float invZ = 1.f / Z;
#pragma unroll
    for (int e = 0; e < E_NUM; ++e) probs[e] *= invZ;

    // stable top-3 (strict >, lowest index wins ties) == jax.lax.top_k
    int i0 = 0; float b0 = probs[0];
#pragma unroll
    for (int e = 1; e < E_NUM; ++e) if (probs[e] > b0) { b0 = probs[e]; i0 = e; }
    int i1 = -1; float b1 = -1.f;
#pragma unroll
    for (int e = 0; e < E_NUM; ++e) if (e != i0 && probs[e] > b1) { b1 = probs[e]; i1 = e; }
    int i2 = -1; float b2 = -1.f;
#pragma unroll
    for (int e = 0; e < E_NUM; ++e) if (e != i0 && e != i1 && probs[e] > b2) { b2 = probs[e]; i2 = e; }

    const float wnorm = 1.f / (b0 + b1 + b2);
    const size_t row = r0 + l;
    float* ow = out + row * 3;
    ow[0] = b0 * wnorm; ow[1] = b1 * wnorm; ow[2] = b2 * wnorm;
    float* oi = out + (size_t)B * 3 + row * 3;
    oi[0] = (float)i0; oi[1] = (float)i1; oi[2] = (float)i2;
    float* op = out + (size_t)B * 6 + row * E_NUM;
#pragma unroll
    for (int e = 0; e < E_NUM; ++e) op[e] = probs[e];
  }
}

extern "C" void kernel_launch(void* const* d_in, const int* in_sizes, int n_in,
                              void* d_out, int out_size, void* d_ws, size_t ws_size,
                              hipStream_t stream) {
  const float* feat  = (const float*)d_in[0];
  const float* Wp    = (const float*)d_in[1];
  const float* bp    = (const float*)d_in[2];
  const float* emb   = (const float*)d_in[3];
  const float* ef    = (const float*)d_in[4];
  const float* trust = (const float*)d_in[5];
  const float* dtv   = (const float*)d_in[6];
  float* out = (float*)d_out;

  float* pk = (float*)d_ws;                    // 512*20 = 10240 floats
  float* cf = pk + D_DIM * 20;                 // E_NUM
  float* bg = cf + E_NUM;                      // E_NUM

  const int B = in_sizes[0] / D_DIM;

  hipLaunchKernelGGL(pre_wg, dim3((E_NUM * D_DIM + E_NUM + 255) / 256), dim3(256),
                     0, stream, Wp, bp, emb, pk, bg);
  hipLaunchKernelGGL(pre_en, dim3(E_NUM), dim3(64), 0, stream, ef, trust, dtv, pk, cf);
  hipLaunchKernelGGL(router_main, dim3(B / 64), dim3(256), 0, stream,
                     feat, pk, cf, bg, out, B);
}

// Round 10
// 72.862 us; speedup vs baseline: 1.3283x; 1.1199x over previous
//
#include <hip/hip_runtime.h>
#include <stdint.h>
#include <math.h>

#define D_DIM 512
#define H_DIM 256
#define E_NUM 10

typedef float f16v __attribute__((ext_vector_type(16)));
typedef float f2 __attribute__((ext_vector_type(2)));

// ---------- precompute: packed weights pk[d][gate e0..9 | sim e0..9] + bias_g ----------
__global__ __launch_bounds__(256) void pre_wg(const float* __restrict__ Wp,
                                              const float* __restrict__ bp,
                                              const float* __restrict__ emb,
                                              float* __restrict__ pk,
                                              float* __restrict__ bg) {
  int gid = blockIdx.x * 256 + threadIdx.x;
  if (gid < E_NUM * D_DIM) {
    int d = gid / E_NUM;
    int e = gid - d * E_NUM;
    const float* wr = Wp + (size_t)d * H_DIM;
    const float* er = emb + (size_t)e * H_DIM;
    float s0 = 0.f, s1 = 0.f, s2 = 0.f, s3 = 0.f;
#pragma unroll 4
    for (int h = 0; h < H_DIM; h += 4) {
      float4 a = *(const float4*)(wr + h);
      float4 b = *(const float4*)(er + h);
      s0 = fmaf(a.x, b.x, s0); s1 = fmaf(a.y, b.y, s1);
      s2 = fmaf(a.z, b.z, s2); s3 = fmaf(a.w, b.w, s3);
    }
    pk[(size_t)d * 20 + e] = ((s0 + s1) + (s2 + s3)) * 0.0625f;
  } else if (gid < E_NUM * D_DIM + E_NUM) {
    int e = gid - E_NUM * D_DIM;
    const float* er = emb + (size_t)e * H_DIM;
    float s = 0.f;
    for (int h = 0; h < H_DIM; ++h) s = fmaf(bp[h], er[h], s);
    bg[e] = s * 0.0625f;
  }
}

// ---------- precompute: normalized expert rows into pk sim slots + trust*stale ----------
__global__ __launch_bounds__(64) void pre_en(const float* __restrict__ ef,
                                             const float* __restrict__ trust,
                                             const float* __restrict__ dtv,
                                             float* __restrict__ pk,
                                             float* __restrict__ cf) {
  int e = blockIdx.x, l = threadIdx.x;
  const float* row = ef + (size_t)e * D_DIM;
  float s = 0.f;
#pragma unroll
  for (int j = 0; j < D_DIM / 64; ++j) { float v = row[l + 64 * j]; s = fmaf(v, v, s); }
#pragma unroll
  for (int o = 32; o; o >>= 1) s += __shfl_xor(s, o, 64);
  float inv = 1.f / fmaxf(sqrtf(s), 1e-8f);
#pragma unroll
  for (int j = 0; j < D_DIM / 64; ++j) {
    int d = l + 64 * j;
    pk[(size_t)d * 20 + 10 + e] = row[d] * inv;
  }
  if (l == 0) cf[e] = trust[e] * expf(-0.001f * dtv[e]);
}

// element i (0..79) of the 5 SGPR x16 vectors; i compile-time under unroll
#define WVx(i) ((i) < 16 ? w0[(i) & 15] : (i) < 32 ? w1[(i) & 15] : \
                (i) < 48 ? w2[(i) & 15] : (i) < 64 ? w3[(i) & 15] : w4[(i) & 15])

// ---------- main: block-cooperative coalesced staging (8 lines/load), 3-buf
// counted-vmcnt pipeline with barrier-then-stage ordering, SGPR weights, pk-fma ----------
__global__ __launch_bounds__(256, 6) void router_main(
    const float* __restrict__ feat, const float* __restrict__ pk,
    const float* __restrict__ cf, const float* __restrict__ bg,
    float* __restrict__ out, int B) {
  __shared__ float lds[6144];                             // 3 bufs x 8 KB
  const int t = threadIdx.x;
  const int l = t & 63;
  const int w = __builtin_amdgcn_readfirstlane(t >> 6);   // wave = d-octant pair
  const size_t r0 = (size_t)blockIdx.x * 64;

  // staging: wave w, call j stages rows w*16+j*8+(l>>3); 8 rows x 128B contiguous
  // per load inst (8 cache lines). Source d-quad XOR-pre-swizzled so the LINEAR
  // gload_lds dest realizes LDS cell (row r, slot s) = d-quad (s ^ (r&7)).
  const float* gsrc = feat + (r0 + w * 16 + (l >> 3)) * (size_t)D_DIM
                      + (((l & 7) ^ (l >> 3)) << 2);
  const int dst0 = w * 512 + (l << 2);                    // floats

  f2 ag[5], as_[5], n2;
#pragma unroll
  for (int i = 0; i < 5; ++i) { ag[i] = f2{0.f, 0.f}; as_[i] = f2{0.f, 0.f}; }
  n2 = f2{0.f, 0.f};

  auto STAGE = [&](int buf, int c) {
#pragma unroll
    for (int j = 0; j < 2; ++j) {
      __builtin_amdgcn_global_load_lds(
          (const __attribute__((address_space(1))) uint32_t*)(gsrc + (size_t)j * 8 * D_DIM + c * 32),
          (__attribute__((address_space(3))) uint32_t*)&lds[buf * 2048 + dst0 + j * 256],
          16, 0, 0);
    }
  };

  auto COMPUTE = [&](int buf, int c) {
#pragma unroll
    for (int sub = 0; sub < 2; ++sub) {
      f16v w0, w1, w2, w3, w4;
      const float* wp = pk + (size_t)(c * 32 + w * 8 + sub * 4) * 20;  // wave-uniform
      asm volatile(
          "s_load_dwordx16 %0, %5, 0x0\n"
          "s_load_dwordx16 %1, %5, 0x40\n"
          "s_load_dwordx16 %2, %5, 0x80\n"
          "s_load_dwordx16 %3, %5, 0xc0\n"
          "s_load_dwordx16 %4, %5, 0x100\n"
          "s_waitcnt lgkmcnt(0)"
          : "=&s"(w0), "=&s"(w1), "=&s"(w2), "=&s"(w3), "=&s"(w4)
          : "s"(wp));
      const int slot = (2 * w + sub) ^ (l & 7);           // bank-spreading swizzle
      float4 f = *(const float4*)&lds[buf * 2048 + l * 32 + slot * 4];
#pragma unroll
      for (int q = 0; q < 4; ++q) {
        const float fq = (q == 0) ? f.x : (q == 1) ? f.y : (q == 2) ? f.z : f.w;
        const f2 fq2 = {fq, fq};
#pragma unroll
        for (int j = 0; j < 5; ++j) {
          const int bgi = q * 20 + 2 * j;
          f2 wg2 = {WVx(bgi), WVx(bgi + 1)};
          ag[j] = __builtin_elementwise_fma(fq2, wg2, ag[j]);
        }
#pragma unroll
        for (int j = 0; j < 5; ++j) {
          const int bsi = q * 20 + 10 + 2 * j;
          f2 ws2 = {WVx(bsi), WVx(bsi + 1)};
          as_[j] = __builtin_elementwise_fma(fq2, ws2, as_[j]);
        }
      }
      f2 p0 = {f.x, f.y}, p1 = {f.z, f.w};
      n2 = __builtin_elementwise_fma(p0, p0, n2);
      n2 = __builtin_elementwise_fma(p1, p1, n2);
    }
  };

  // R9 RACE FIX: barrier BEFORE compute. Per iteration:
  //   vmcnt(2): own chunk-c loads landed (2 insts for chunk c+1 stay in flight)
  //   s_barrier: ALL waves' chunk-c loads landed; all reads of chunk c-1 sealed
  //   STAGE(c+2): overwrites buf holding chunk c-1 -- sealed by this barrier
  //   COMPUTE(c); lgkmcnt(0): own ds_reads retired before next barrier
  STAGE(0, 0); STAGE(1, 1);
  int cb = 0, sb = 2;
#pragma unroll 1
  for (int c = 0; c < 16; ++c) {
    if (c < 15) asm volatile("s_waitcnt vmcnt(2)" ::: "memory");
    else        asm volatile("s_waitcnt vmcnt(0)" ::: "memory");
    __builtin_amdgcn_s_barrier();
    __builtin_amdgcn_sched_barrier(0);
    if (c < 14) STAGE(sb, c + 2);
    COMPUTE(cb, c);
    asm volatile("s_waitcnt lgkmcnt(0)" ::: "memory");
    __builtin_amdgcn_sched_barrier(0);
    cb = (cb == 2) ? 0 : cb + 1;
    sb = (sb == 2) ? 0 : sb + 1;
  }
  __syncthreads();   // seal ALL waves' final reads before reduction writes alias bufs

  float acc[21];
#pragma unroll
  for (int e = 0; e < E_NUM; ++e) { acc[e] = ag[e >> 1][e & 1]; acc[10 + e] = as_[e >> 1][e & 1]; }
  acc[20] = n2.x + n2.y;

  // ---------- cross-wave reduction ----------
  if (w) {
    float* rp = &lds[(w - 1) * 1344 + l * 21];
#pragma unroll
    for (int i = 0; i < 21; ++i) rp[i] = acc[i];
  }
  __syncthreads();
  if (w == 0) {
#pragma unroll
    for (int s = 0; s < 3; ++s) {
      const float* rp = &lds[s * 1344 + l * 21];
#pragma unroll
      for (int i = 0; i < 21; ++i) acc[i] += rp[i];
    }

    const float inv = 1.f / fmaxf(sqrtf(acc[20]), 1e-8f);
    float probs[E_NUM];
    float m = -1e30f;
#pragma unroll
    for (int e = 0; e < E_NUM; ++e) {
      float logit = acc[e] + bg[e];
      float gate = 1.f / (1.f + __expf(-logit));
      float sim = fmaf(acc[10 + e] * inv, 0.5f, 0.5f);
      float sc = gate * cf[e] * sim;
      probs[e] = sc;
      m = fmaxf(m, sc);
    }
    float Z = 0.f;
#pragma unroll
    for (int e = 0; e < E_NUM; ++e) { float pe = __expf(probs[e] - m); probs[e] = pe; Z += pe; }
    const float invZ = 1.f / Z;
#pragma unroll
    for (int e = 0; e < E_NUM; ++e) probs[e] *= invZ;

    // stable top-3 (strict >, lowest index wins ties) == jax.lax.top_k
    int i0 = 0; float b0 = probs[0];
#pragma unroll
    for (int e = 1; e < E_NUM; ++e) if (probs[e] > b0) { b0 = probs[e]; i0 = e; }
    int i1 = -1; float b1 = -1.f;
#pragma unroll
    for (int e = 0; e < E_NUM; ++e) if (e != i0 && probs[e] > b1) { b1 = probs[e]; i1 = e; }
    int i2 = -1; float b2 = -1.f;
#pragma unroll
    for (int e = 0; e < E_NUM; ++e) if (e != i0 && e != i1 && probs[e] > b2) { b2 = probs[e]; i2 = e; }

    const float wnorm = 1.f / (b0 + b1 + b2);
    const size_t row = r0 + l;
    float* ow = out + row * 3;
    ow[0] = b0 * wnorm; ow[1] = b1 * wnorm; ow[2] = b2 * wnorm;
    float* oi = out + (size_t)B * 3 + row * 3;
    oi[0] = (float)i0; oi[1] = (float)i1; oi[2] = (float)i2;
    float* op = out + (size_t)B * 6 + row * E_NUM;
#pragma unroll
    for (int e = 0; e < E_NUM; ++e) op[e] = probs[e];
  }
}

extern "C" void kernel_launch(void* const* d_in, const int* in_sizes, int n_in,
                              void* d_out, int out_size, void* d_ws, size_t ws_size,
                              hipStream_t stream) {
  const float* feat  = (const float*)d_in[0];
  const float* Wp    = (const float*)d_in[1];
  const float* bp    = (const float*)d_in[2];
  const float* emb   = (const float*)d_in[3];
  const float* ef    = (const float*)d_in[4];
  const float* trust = (const float*)d_in[5];
  const float* dtv   = (const float*)d_in[6];
  float* out = (float*)d_out;

  float* pk = (float*)d_ws;                    // 512*20 = 10240 floats
  float* cf = pk + D_DIM * 20;                 // E_NUM
  float* bg = cf + E_NUM;                      // E_NUM

  const int B = in_sizes[0] / D_DIM;

  hipLaunchKernelGGL(pre_wg, dim3((E_NUM * D_DIM + E_NUM + 255) / 256), dim3(256),
                     0, stream, Wp, bp, emb, pk, bg);
  hipLaunchKernelGGL(pre_en, dim3(E_NUM), dim3(64), 0, stream, ef, trust, dtv, pk, cf);
  hipLaunchKernelGGL(router_main, dim3(B / 64), dim3(256), 0, stream,
                     feat, pk, cf, bg, out, B);
}

// Round 11
// 69.163 us; speedup vs baseline: 1.3993x; 1.0535x over previous
//
#include <hip/hip_runtime.h>
#include <stdint.h>
#include <math.h>

#define D_DIM 512
#define H_DIM 256
#define E_NUM 10

typedef float f16v __attribute__((ext_vector_type(16)));
typedef float f2 __attribute__((ext_vector_type(2)));

// ---------- merged precompute ----------
// blocks 0..19: pk[d*20+e] = dot(Wp[d,:], emb[e,:])/16   (gate weights)
// block 20:     bg/cf (wave0 lanes<10) + normalized expert rows into pk sim slots
__global__ __launch_bounds__(256) void pre_all(const float* __restrict__ Wp,
                                               const float* __restrict__ bp,
                                               const float* __restrict__ emb,
                                               const float* __restrict__ ef,
                                               const float* __restrict__ trust,
                                               const float* __restrict__ dtv,
                                               float* __restrict__ pk,
                                               float* __restrict__ bg,
                                               float* __restrict__ cf) {
  const int bid = blockIdx.x;
  if (bid < 20) {
    int gid = bid * 256 + threadIdx.x;
    if (gid < E_NUM * D_DIM) {
      int d = gid / E_NUM;
      int e = gid - d * E_NUM;
      const float* wr = Wp + (size_t)d * H_DIM;
      const float* er = emb + (size_t)e * H_DIM;
      float s0 = 0.f, s1 = 0.f, s2 = 0.f, s3 = 0.f;
#pragma unroll 4
      for (int h = 0; h < H_DIM; h += 4) {
        float4 a = *(const float4*)(wr + h);
        float4 b = *(const float4*)(er + h);
        s0 = fmaf(a.x, b.x, s0); s1 = fmaf(a.y, b.y, s1);
        s2 = fmaf(a.z, b.z, s2); s3 = fmaf(a.w, b.w, s3);
      }
      pk[(size_t)d * 20 + e] = ((s0 + s1) + (s2 + s3)) * 0.0625f;
    }
  } else {
    const int t = threadIdx.x;
    const int l = t & 63;
    const int w = t >> 6;
    if (w == 0 && l < E_NUM) {
      const float* er = emb + (size_t)l * H_DIM;
      float s = 0.f;
      for (int h = 0; h < H_DIM; ++h) s = fmaf(bp[h], er[h], s);
      bg[l] = s * 0.0625f;
      cf[l] = trust[l] * expf(-0.001f * dtv[l]);
    }
    for (int e = w; e < E_NUM; e += 4) {
      const float* row = ef + (size_t)e * D_DIM;
      float s = 0.f;
#pragma unroll
      for (int j = 0; j < D_DIM / 64; ++j) { float v = row[l + 64 * j]; s = fmaf(v, v, s); }
#pragma unroll
      for (int o = 32; o; o >>= 1) s += __shfl_xor(s, o, 64);
      float inv = 1.f / fmaxf(sqrtf(s), 1e-8f);
#pragma unroll
      for (int j = 0; j < D_DIM / 64; ++j) {
        int d = l + 64 * j;
        pk[(size_t)d * 20 + 10 + e] = row[d] * inv;
      }
    }
  }
}

// element i (0..79) of the 5 SGPR x16 vectors; i compile-time under unroll
#define WVx(i) ((i) < 16 ? w0[(i) & 15] : (i) < 32 ? w1[(i) & 15] : \
                (i) < 48 ? w2[(i) & 15] : (i) < 64 ? w3[(i) & 15] : w4[(i) & 15])

// ---------- main: block-cooperative staging (8 lines/load), 4-buf DEPTH-3
// counted-vmcnt pipeline, SGPR weights, pk-fma ----------
__global__ __launch_bounds__(256, 5) void router_main(
    const float* __restrict__ feat, const float* __restrict__ pk,
    const float* __restrict__ cf, const float* __restrict__ bg,
    float* __restrict__ out, int B) {
  __shared__ float lds[8192];                             // 4 bufs x 8 KB
  const int t = threadIdx.x;
  const int l = t & 63;
  const int w = __builtin_amdgcn_readfirstlane(t >> 6);
  const size_t r0 = (size_t)blockIdx.x * 64;

  // staging: wave w, call j stages rows w*16+j*8+(l>>3); 8 rows x 128B contiguous
  // per load (8 cache lines). Source d-quad XOR-pre-swizzled so the LINEAR
  // gload_lds dest realizes LDS cell (row r, slot s) = d-quad (s ^ (r&7)).
  const float* gsrc = feat + (r0 + w * 16 + (l >> 3)) * (size_t)D_DIM
                      + (((l & 7) ^ (l >> 3)) << 2);
  const int dst0 = w * 512 + (l << 2);                    // floats

  f2 ag[5], as_[5], n2;
#pragma unroll
  for (int i = 0; i < 5; ++i) { ag[i] = f2{0.f, 0.f}; as_[i] = f2{0.f, 0.f}; }
  n2 = f2{0.f, 0.f};

  auto STAGE = [&](int c) {
#pragma unroll
    for (int j = 0; j < 2; ++j) {
      __builtin_amdgcn_global_load_lds(
          (const __attribute__((address_space(1))) uint32_t*)(gsrc + (size_t)j * 8 * D_DIM + c * 32),
          (__attribute__((address_space(3))) uint32_t*)&lds[(c & 3) * 2048 + dst0 + j * 256],
          16, 0, 0);
    }
  };

  auto COMPUTE = [&](int c) {
    const int buf = c & 3;
#pragma unroll
    for (int sub = 0; sub < 2; ++sub) {
      f16v w0, w1, w2, w3, w4;
      const float* wp = pk + (size_t)(c * 32 + w * 8 + sub * 4) * 20;  // wave-uniform
      asm volatile(
          "s_load_dwordx16 %0, %5, 0x0\n"
          "s_load_dwordx16 %1, %5, 0x40\n"
          "s_load_dwordx16 %2, %5, 0x80\n"
          "s_load_dwordx16 %3, %5, 0xc0\n"
          "s_load_dwordx16 %4, %5, 0x100\n"
          "s_waitcnt lgkmcnt(0)"
          : "=&s"(w0), "=&s"(w1), "=&s"(w2), "=&s"(w3), "=&s"(w4)
          : "s"(wp));
      const int slot = (2 * w + sub) ^ (l & 7);           // bank-spreading swizzle
      float4 f = *(const float4*)&lds[buf * 2048 + l * 32 + slot * 4];
#pragma unroll
      for (int q = 0; q < 4; ++q) {
        const float fq = (q == 0) ? f.x : (q == 1) ? f.y : (q == 2) ? f.z : f.w;
        const f2 fq2 = {fq, fq};
#pragma unroll
        for (int j = 0; j < 5; ++j) {
          const int bgi = q * 20 + 2 * j;
          f2 wg2 = {WVx(bgi), WVx(bgi + 1)};
          ag[j] = __builtin_elementwise_fma(fq2, wg2, ag[j]);
        }
#pragma unroll
        for (int j = 0; j < 5; ++j) {
          const int bsi = q * 20 + 10 + 2 * j;
          f2 ws2 = {WVx(bsi), WVx(bsi + 1)};
          as_[j] = __builtin_elementwise_fma(fq2, ws2, as_[j]);
        }
      }
      f2 p0 = {f.x, f.y}, p1 = {f.z, f.w};
      n2 = __builtin_elementwise_fma(p0, p0, n2);
      n2 = __builtin_elementwise_fma(p1, p1, n2);
    }
  };

  // Depth-3 pipeline. Per iter:
  //   vmcnt(N): own chunk-c loads landed (chunks c+1..c+3 stay in flight)
  //   s_barrier: ALL waves' chunk-c landed; all reads of chunk c-1 sealed
  //   STAGE(c+3): overwrites buf of chunk c-1 -- sealed by this barrier
  //   COMPUTE(c); lgkmcnt(0): own ds_reads retired before next barrier
  STAGE(0); STAGE(1); STAGE(2);
#pragma unroll 1
  for (int c = 0; c < 16; ++c) {
    if (c <= 13)      asm volatile("s_waitcnt vmcnt(4)" ::: "memory");
    else if (c == 14) asm volatile("s_waitcnt vmcnt(2)" ::: "memory");
    else              asm volatile("s_waitcnt vmcnt(0)" ::: "memory");
    __builtin_amdgcn_s_barrier();
    __builtin_amdgcn_sched_barrier(0);
    if (c < 13) STAGE(c + 3);
    COMPUTE(c);
    asm volatile("s_waitcnt lgkmcnt(0)" ::: "memory");
    __builtin_amdgcn_sched_barrier(0);
  }
  __syncthreads();   // seal all waves' final reads before reduction writes alias bufs

  float acc[21];
#pragma unroll
  for (int e = 0; e < E_NUM; ++e) { acc[e] = ag[e >> 1][e & 1]; acc[10 + e] = as_[e >> 1][e & 1]; }
  acc[20] = n2.x + n2.y;

  // ---------- cross-wave reduction ----------
  if (w) {
    float* rp = &lds[(w - 1) * 1344 + l * 21];
#pragma unroll
    for (int i = 0; i < 21; ++i) rp[i] = acc[i];
  }
  __syncthreads();
  if (w == 0) {
#pragma unroll
    for (int s = 0; s < 3; ++s) {
      const float* rp = &lds[s * 1344 + l * 21];
#pragma unroll
      for (int i = 0; i < 21; ++i) acc[i] += rp[i];
    }

    const float inv = 1.f / fmaxf(sqrtf(acc[20]), 1e-8f);
    float probs[E_NUM];
    float m = -1e30f;
#pragma unroll
    for (int e = 0; e < E_NUM; ++e) {
      float logit = acc[e] + bg[e];
      float gate = 1.f / (1.f + __expf(-logit));
      float sim = fmaf(acc[10 + e] * inv, 0.5f, 0.5f);
      float sc = gate * cf[e] * sim;
      probs[e] = sc;
      m = fmaxf(m, sc);
    }
    float Z = 0.f;
#pragma unroll
    for (int e = 0; e < E_NUM; ++e) { float pe = __expf(probs[e] - m); probs[e] = pe; Z += pe; }
    const float invZ = 1.f / Z;
#pragma unroll
    for (int e = 0; e < E_NUM; ++e) probs[e] *= invZ;

    // stable top-3 (strict >, lowest index wins ties) == jax.lax.top_k
    int i0 = 0; float b0 = probs[0];
#pragma unroll
    for (int e = 1; e < E_NUM; ++e) if (probs[e] > b0) { b0 = probs[e]; i0 = e; }
    int i1 = -1; float b1 = -1.f;
#pragma unroll
    for (int e = 0; e < E_NUM; ++e) if (e != i0 && probs[e] > b1) { b1 = probs[e]; i1 = e; }
    int i2 = -1; float b2 = -1.f;
#pragma unroll
    for (int e = 0; e < E_NUM; ++e) if (e != i0 && e != i1 && probs[e] > b2) { b2 = probs[e]; i2 = e; }

    const float wnorm = 1.f / (b0 + b1 + b2);
    const size_t row = r0 + l;
    float* ow = out + row * 3;
    ow[0] = b0 * wnorm; ow[1] = b1 * wnorm; ow[2] = b2 * wnorm;
    float* oi = out + (size_t)B * 3 + row * 3;
    oi[0] = (float)i0; oi[1] = (float)i1; oi[2] = (float)i2;
    float* op = out + (size_t)B * 6 + row * E_NUM;
#pragma unroll
    for (int e = 0; e < E_NUM; ++e) op[e] = probs[e];
  }
}

extern "C" void kernel_launch(void* const* d_in, const int* in_sizes, int n_in,
                              void* d_out, int out_size, void* d_ws, size_t ws_size,
                              hipStream_t stream) {
  const float* feat  = (const float*)d_in[0];
  const float* Wp    = (const float*)d_in[1];
  const float* bp    = (const float*)d_in[2];
  const float* emb   = (const float*)d_in[3];
  const float* ef    = (const float*)d_in[4];
  const float* trust = (const float*)d_in[5];
  const float* dtv   = (const float*)d_in[6];
  float* out = (float*)d_out;

  float* pk = (float*)d_ws;                    // 512*20 = 10240 floats
  float* cf = pk + D_DIM * 20;                 // E_NUM
  float* bg = cf + E_NUM;                      // E_NUM

  const int B = in_sizes[0] / D_DIM;

  hipLaunchKernelGGL(pre_all, dim3(21), dim3(256), 0, stream,
                     Wp, bp, emb, ef, trust, dtv, pk, bg, cf);
  hipLaunchKernelGGL(router_main, dim3(B / 64), dim3(256), 0, stream,
                     feat, pk, cf, bg, out, B);
}